// Round 8
// baseline (523.491 us; speedup 1.0000x reference)
//
#include <hip/hip_runtime.h>
#include <stdint.h>

#define BLOCK 256
#define NPART 4            // clause-space partitions (2 XCDs per partition)
#define CHUNK 8192         // edges per grab: 2048 iv4s = 8/thread (unroll-friendly)

typedef int iv4 __attribute__((ext_vector_type(4)));

// ---------------------------------------------------------------------------
// ws layout:
//   [0]        nsat counter
//   [1]        done ticket
//   [2..5]     work-steal cursors[NPART]
//   [64 ..)    predbits : 1 bit per var, ((n_vars+63)/64)*8 bytes (~128 KB)
//   [satoff..) sat      : 1 BYTE per clause (~4 MB), plain stores
// All rebuilt every call (ws re-poisoned to 0xAA before every timed launch).
// ---------------------------------------------------------------------------

__global__ void prep(const float* __restrict__ preds,
                     unsigned long long* __restrict__ predbits,
                     uint4* __restrict__ satz,
                     unsigned* __restrict__ hdr,
                     int n_vars,
                     const int* __restrict__ nc_p) {
    const int gid = blockIdx.x * blockDim.x + threadIdx.x;
    const int stride = gridDim.x * blockDim.x;

    const int nv64 = (n_vars + 63) & ~63;
    for (int i = gid; i < nv64; i += stride) {
        bool b = false;
        if (i < n_vars) b = (preds[i] >= 0.5f);
        const unsigned long long m = __ballot(b);
        if ((threadIdx.x & 63) == 0) predbits[i >> 6] = m;
    }

    const int nc = *nc_p;
    const int satw16 = (nc + 15) >> 4;
    const uint4 z = {0u, 0u, 0u, 0u};
    for (int i = gid; i < satw16; i += stride) satz[i] = z;

    if (gid < 8) hdr[gid] = 0u;   // nsat, done, cursors[4], pad
}

__device__ __forceinline__ void proc4(iv4 l, iv4 c, unsigned lo, unsigned psize,
                                      int nv,
                                      const unsigned* __restrict__ predbits,
                                      unsigned char* __restrict__ sat) {
    #pragma unroll
    for (int k = 0; k < 4; ++k) {
        const int lit = l[k];
        const int cls = c[k];
        if ((unsigned)cls - lo < psize) {            // ours? (check BEFORE gather)
            const bool pos = lit < nv;
            const int v = pos ? lit : lit - nv;
            const unsigned pb = predbits[v >> 5];    // hot 128 KB, L2-served
            const bool pbit = ((pb >> (v & 31)) & 1u) != 0u;
            if (pbit == pos) sat[cls] = (unsigned char)1;
        }
    }
}

__global__ void scatter_sat(const int* __restrict__ lits,
                            const int* __restrict__ clauses,
                            const unsigned* __restrict__ predbits,
                            unsigned char* __restrict__ sat,
                            unsigned* __restrict__ cursors,
                            int n_edges, int n_vars,
                            const int* __restrict__ nc_p) {
    // physical XCD -> clause partition (locality only; any mapping is correct)
    unsigned xcd;
    asm volatile("s_getreg_b32 %0, hwreg(HW_REG_XCC_ID)" : "=s"(xcd));
    const unsigned part = (xcd & 7u) >> 1;           // 8 XCDs -> 4 partitions

    const int nc = *nc_p;
    const unsigned psize = (unsigned)((nc + NPART - 1) / NPART);
    const unsigned lo = part * psize;

    const iv4* __restrict__ l4 = reinterpret_cast<const iv4*>(lits);
    const iv4* __restrict__ c4 = reinterpret_cast<const iv4*>(clauses);

    __shared__ unsigned s_base;
    for (;;) {
        if (threadIdx.x == 0)
            s_base = atomicAdd(&cursors[part], (unsigned)CHUNK);
        __syncthreads();
        const unsigned base = s_base;
        __syncthreads();                  // s_base consumed before next grab
        if (base >= (unsigned)n_edges) break;

        if (base + (unsigned)CHUNK <= (unsigned)n_edges) {
            // full chunk: 8 iv4s/thread, unrolled pairs -> >=4 loads in flight
            int i = (int)(base >> 2) + (int)threadIdx.x;
            #pragma unroll
            for (int u = 0; u < 4; ++u) {
                const iv4 l0 = l4[i];
                const iv4 c0 = c4[i];
                const iv4 l1 = l4[i + BLOCK];
                const iv4 c1 = c4[i + BLOCK];
                proc4(l0, c0, lo, psize, n_vars, predbits, sat);
                proc4(l1, c1, lo, psize, n_vars, predbits, sat);
                i += 2 * BLOCK;
            }
        } else {
            // partial last chunk: guarded vector sweep + scalar tail
            const unsigned end = (unsigned)n_edges;
            const int i4b = (int)(base >> 2);
            const int i4e = (int)(end >> 2);
            for (int i = i4b + (int)threadIdx.x; i < i4e; i += BLOCK) {
                const iv4 l = l4[i];
                const iv4 c = c4[i];
                proc4(l, c, lo, psize, n_vars, predbits, sat);
            }
            for (unsigned i = (unsigned)(i4e << 2) + threadIdx.x; i < end; i += BLOCK) {
                const int lit = lits[i];
                const int cls = clauses[i];
                if ((unsigned)cls - lo < psize) {
                    const bool pos = lit < n_vars;
                    const int v = pos ? lit : lit - n_vars;
                    const unsigned pb = predbits[v >> 5];
                    const bool pbit = ((pb >> (v & 31)) & 1u) != 0u;
                    if (pbit == pos) sat[cls] = (unsigned char)1;
                }
            }
        }
    }
}

__global__ void reduce_finalize(const uint4* __restrict__ sat16,
                                unsigned* __restrict__ nsat,
                                unsigned* __restrict__ done,
                                float* __restrict__ out,
                                const int* __restrict__ nc_p,
                                int n_vars) {
    const int nc = *nc_p;
    const int n16 = (nc + 15) >> 4;     // padded bytes zeroed by prep
    const int tid = blockIdx.x * blockDim.x + threadIdx.x;
    const int stride = gridDim.x * blockDim.x;

    unsigned acc = 0;
    for (int i = tid; i < n16; i += stride) {
        const uint4 v = sat16[i];
        acc += __popc(v.x & 0x01010101u) + __popc(v.y & 0x01010101u) +
               __popc(v.z & 0x01010101u) + __popc(v.w & 0x01010101u);
    }

    #pragma unroll
    for (int off = 32; off > 0; off >>= 1) acc += __shfl_down(acc, off);

    __shared__ unsigned smem[BLOCK / 64];
    const int lane = threadIdx.x & 63;
    const int wid  = threadIdx.x >> 6;
    if (lane == 0) smem[wid] = acc;
    __syncthreads();

    if (threadIdx.x == 0) {
        unsigned bsum = 0;
        #pragma unroll
        for (int w = 0; w < BLOCK / 64; ++w) bsum += smem[w];
        atomicAdd(nsat, bsum);
        __threadfence();
        const unsigned ticket = atomicAdd(done, 1u);
        if (ticket == (unsigned)(gridDim.x - 1)) {
            const unsigned total = atomicAdd(nsat, 0u);
            *out = ((float)nc - (float)total) / (float)n_vars;
        }
    }
}

extern "C" void kernel_launch(void* const* d_in, const int* in_sizes, int n_in,
                              void* d_out, int out_size, void* d_ws, size_t ws_size,
                              hipStream_t stream) {
    const float* preds   = (const float*)d_in[0];
    const int*   lits    = (const int*)d_in[1];
    const int*   clauses = (const int*)d_in[2];
    const int*   nc_p    = (const int*)d_in[4];   // n_clauses (device scalar)
    const int    n_vars  = in_sizes[0];
    const int    n_edges = in_sizes[1];

    float* out = (float*)d_out;
    unsigned char* ws = (unsigned char*)d_ws;
    unsigned* hdr = (unsigned*)ws;                 // [0]=nsat [1]=done [2..5]=cursors
    unsigned long long* predbits = (unsigned long long*)(ws + 64);
    const size_t predbits_bytes = ((size_t)((n_vars + 63) / 64)) * 8;
    size_t satoff = 64 + predbits_bytes;
    satoff = (satoff + 63) & ~(size_t)63;          // 64B align sat array
    unsigned char* sat = ws + satoff;

    prep<<<2048, BLOCK, 0, stream>>>(preds, predbits, (uint4*)sat, hdr,
                                     n_vars, nc_p);
    scatter_sat<<<2048, BLOCK, 0, stream>>>(lits, clauses,
                                            (const unsigned*)predbits, sat,
                                            hdr + 2, n_edges, n_vars, nc_p);
    reduce_finalize<<<256, BLOCK, 0, stream>>>((const uint4*)sat,
                                               hdr, hdr + 1, out, nc_p, n_vars);
}

// Round 9
// 471.513 us; speedup vs baseline: 1.1102x; 1.1102x over previous
//
#include <hip/hip_runtime.h>
#include <stdint.h>

#define BLOCK 256
#define NPART 2            // clause-space partitions (4 XCDs per partition)
#define CHUNK 8192         // edges per grab: 2048 iv4s = 8 iv4-pairs per thread

typedef int iv4 __attribute__((ext_vector_type(4)));

// ---------------------------------------------------------------------------
// ws layout:
//   [0]        nsat counter
//   [1]        done ticket
//   [2..3]     work-steal cursors[NPART]
//   [64 ..)    predbits : 1 bit per var, ((n_vars+63)/64)*8 bytes (~128 KB)
//   [satoff..) sat      : 1 BYTE per clause (~4 MB), plain stores
// All rebuilt every call (ws re-poisoned to 0xAA before every timed launch).
// ---------------------------------------------------------------------------

__global__ void prep(const float* __restrict__ preds,
                     unsigned long long* __restrict__ predbits,
                     uint4* __restrict__ satz,
                     unsigned* __restrict__ hdr,
                     int n_vars,
                     const int* __restrict__ nc_p) {
    const int gid = blockIdx.x * blockDim.x + threadIdx.x;
    const int stride = gridDim.x * blockDim.x;

    const int nv64 = (n_vars + 63) & ~63;
    for (int i = gid; i < nv64; i += stride) {
        bool b = false;
        if (i < n_vars) b = (preds[i] >= 0.5f);
        const unsigned long long m = __ballot(b);
        if ((threadIdx.x & 63) == 0) predbits[i >> 6] = m;
    }

    const int nc = *nc_p;
    const int satw16 = (nc + 15) >> 4;
    const uint4 z = {0u, 0u, 0u, 0u};
    for (int i = gid; i < satw16; i += stride) satz[i] = z;

    if (gid < 8) hdr[gid] = 0u;   // nsat, done, cursors[2], pad
}

__device__ __forceinline__ void proc4(iv4 l, iv4 c, unsigned lo, unsigned psize,
                                      int nv,
                                      const unsigned* __restrict__ predbits,
                                      unsigned char* __restrict__ sat) {
    #pragma unroll
    for (int k = 0; k < 4; ++k) {
        const int lit = l[k];
        const int cls = c[k];
        if ((unsigned)cls - lo < psize) {            // ours? (check BEFORE gather)
            const bool pos = lit < nv;
            const int v = pos ? lit : lit - nv;
            const unsigned pb = predbits[v >> 5];    // hot 128 KB, L2-served
            const bool pbit = ((pb >> (v & 31)) & 1u) != 0u;
            if (pbit == pos) sat[cls] = (unsigned char)1;
        }
    }
}

__global__ void scatter_sat(const int* __restrict__ lits,
                            const int* __restrict__ clauses,
                            const unsigned* __restrict__ predbits,
                            unsigned char* __restrict__ sat,
                            unsigned* __restrict__ cursors,
                            int n_edges, int n_vars,
                            const int* __restrict__ nc_p) {
    // physical XCD -> clause partition (locality only; correctness is
    // mapping-independent thanks to cross-partition stealing below).
    unsigned xcd;
    asm volatile("s_getreg_b32 %0, hwreg(HW_REG_XCC_ID)" : "=s"(xcd));
    const unsigned mypart = (xcd >> 2) & (NPART - 1);  // XCD 0-3 -> 0, 4-7 -> 1

    const int nc = *nc_p;
    const unsigned psize = (unsigned)((nc + NPART - 1) / NPART);

    const iv4* __restrict__ l4 = reinterpret_cast<const iv4*>(lits);
    const iv4* __restrict__ c4 = reinterpret_cast<const iv4*>(clauses);

    __shared__ unsigned s_base;

    for (unsigned pp = 0; pp < NPART; ++pp) {
        const unsigned part = (mypart + pp) & (NPART - 1);  // own first, then steal
        const unsigned lo = part * psize;

        for (;;) {
            if (threadIdx.x == 0)
                s_base = atomicAdd(&cursors[part], (unsigned)CHUNK);
            __syncthreads();
            const unsigned base = s_base;
            __syncthreads();                  // s_base consumed before next grab
            if (base >= (unsigned)n_edges) break;

            if (base + (unsigned)CHUNK <= (unsigned)n_edges) {
                // full chunk: stage ALL 16 loads (static unroll -> registers),
                // then process. 16-deep MLP per wave.
                const int i0 = (int)(base >> 2) + (int)threadIdx.x;
                iv4 L0, L1, L2, L3, L4, L5, L6, L7;
                iv4 C0, C1, C2, C3, C4, C5, C6, C7;
                L0 = __builtin_nontemporal_load(&l4[i0 + 0 * BLOCK]);
                C0 = __builtin_nontemporal_load(&c4[i0 + 0 * BLOCK]);
                L1 = __builtin_nontemporal_load(&l4[i0 + 1 * BLOCK]);
                C1 = __builtin_nontemporal_load(&c4[i0 + 1 * BLOCK]);
                L2 = __builtin_nontemporal_load(&l4[i0 + 2 * BLOCK]);
                C2 = __builtin_nontemporal_load(&c4[i0 + 2 * BLOCK]);
                L3 = __builtin_nontemporal_load(&l4[i0 + 3 * BLOCK]);
                C3 = __builtin_nontemporal_load(&c4[i0 + 3 * BLOCK]);
                L4 = __builtin_nontemporal_load(&l4[i0 + 4 * BLOCK]);
                C4 = __builtin_nontemporal_load(&c4[i0 + 4 * BLOCK]);
                L5 = __builtin_nontemporal_load(&l4[i0 + 5 * BLOCK]);
                C5 = __builtin_nontemporal_load(&c4[i0 + 5 * BLOCK]);
                L6 = __builtin_nontemporal_load(&l4[i0 + 6 * BLOCK]);
                C6 = __builtin_nontemporal_load(&c4[i0 + 6 * BLOCK]);
                L7 = __builtin_nontemporal_load(&l4[i0 + 7 * BLOCK]);
                C7 = __builtin_nontemporal_load(&c4[i0 + 7 * BLOCK]);
                proc4(L0, C0, lo, psize, n_vars, predbits, sat);
                proc4(L1, C1, lo, psize, n_vars, predbits, sat);
                proc4(L2, C2, lo, psize, n_vars, predbits, sat);
                proc4(L3, C3, lo, psize, n_vars, predbits, sat);
                proc4(L4, C4, lo, psize, n_vars, predbits, sat);
                proc4(L5, C5, lo, psize, n_vars, predbits, sat);
                proc4(L6, C6, lo, psize, n_vars, predbits, sat);
                proc4(L7, C7, lo, psize, n_vars, predbits, sat);
            } else {
                // partial last chunk: guarded vector sweep + scalar tail
                const unsigned end = (unsigned)n_edges;
                const int i4b = (int)(base >> 2);
                const int i4e = (int)(end >> 2);
                for (int i = i4b + (int)threadIdx.x; i < i4e; i += BLOCK) {
                    const iv4 l = __builtin_nontemporal_load(&l4[i]);
                    const iv4 c = __builtin_nontemporal_load(&c4[i]);
                    proc4(l, c, lo, psize, n_vars, predbits, sat);
                }
                for (unsigned i = (unsigned)(i4e << 2) + threadIdx.x; i < end;
                     i += BLOCK) {
                    const int lit = lits[i];
                    const int cls = clauses[i];
                    if ((unsigned)cls - lo < psize) {
                        const bool pos = lit < n_vars;
                        const int v = pos ? lit : lit - n_vars;
                        const unsigned pb = predbits[v >> 5];
                        const bool pbit = ((pb >> (v & 31)) & 1u) != 0u;
                        if (pbit == pos) sat[cls] = (unsigned char)1;
                    }
                }
            }
        }
    }
}

__global__ void reduce_finalize(const uint4* __restrict__ sat16,
                                unsigned* __restrict__ nsat,
                                unsigned* __restrict__ done,
                                float* __restrict__ out,
                                const int* __restrict__ nc_p,
                                int n_vars) {
    const int nc = *nc_p;
    const int n16 = (nc + 15) >> 4;     // padded bytes zeroed by prep
    const int tid = blockIdx.x * blockDim.x + threadIdx.x;
    const int stride = gridDim.x * blockDim.x;

    unsigned acc = 0;
    for (int i = tid; i < n16; i += stride) {
        const uint4 v = sat16[i];
        acc += __popc(v.x & 0x01010101u) + __popc(v.y & 0x01010101u) +
               __popc(v.z & 0x01010101u) + __popc(v.w & 0x01010101u);
    }

    #pragma unroll
    for (int off = 32; off > 0; off >>= 1) acc += __shfl_down(acc, off);

    __shared__ unsigned smem[BLOCK / 64];
    const int lane = threadIdx.x & 63;
    const int wid  = threadIdx.x >> 6;
    if (lane == 0) smem[wid] = acc;
    __syncthreads();

    if (threadIdx.x == 0) {
        unsigned bsum = 0;
        #pragma unroll
        for (int w = 0; w < BLOCK / 64; ++w) bsum += smem[w];
        atomicAdd(nsat, bsum);
        __threadfence();
        const unsigned ticket = atomicAdd(done, 1u);
        if (ticket == (unsigned)(gridDim.x - 1)) {
            const unsigned total = atomicAdd(nsat, 0u);
            *out = ((float)nc - (float)total) / (float)n_vars;
        }
    }
}

extern "C" void kernel_launch(void* const* d_in, const int* in_sizes, int n_in,
                              void* d_out, int out_size, void* d_ws, size_t ws_size,
                              hipStream_t stream) {
    const float* preds   = (const float*)d_in[0];
    const int*   lits    = (const int*)d_in[1];
    const int*   clauses = (const int*)d_in[2];
    const int*   nc_p    = (const int*)d_in[4];   // n_clauses (device scalar)
    const int    n_vars  = in_sizes[0];
    const int    n_edges = in_sizes[1];

    float* out = (float*)d_out;
    unsigned char* ws = (unsigned char*)d_ws;
    unsigned* hdr = (unsigned*)ws;                 // [0]=nsat [1]=done [2..3]=cursors
    unsigned long long* predbits = (unsigned long long*)(ws + 64);
    const size_t predbits_bytes = ((size_t)((n_vars + 63) / 64)) * 8;
    size_t satoff = 64 + predbits_bytes;
    satoff = (satoff + 63) & ~(size_t)63;          // 64B align sat array
    unsigned char* sat = ws + satoff;

    prep<<<2048, BLOCK, 0, stream>>>(preds, predbits, (uint4*)sat, hdr,
                                     n_vars, nc_p);
    scatter_sat<<<2048, BLOCK, 0, stream>>>(lits, clauses,
                                            (const unsigned*)predbits, sat,
                                            hdr + 2, n_edges, n_vars, nc_p);
    reduce_finalize<<<256, BLOCK, 0, stream>>>((const uint4*)sat,
                                               hdr, hdr + 1, out, nc_p, n_vars);
}

// Round 12
// 361.197 us; speedup vs baseline: 1.4493x; 1.3054x over previous
//
#include <hip/hip_runtime.h>
#include <stdint.h>

#define BLOCK 256

typedef int iv4 __attribute__((ext_vector_type(4)));

// ---------------------------------------------------------------------------
// ws layout:
//   [0]        nsat counter
//   [1]        done ticket
//   [64 ..)    predbits : 1 bit per var, ((n_vars+63)/64)*8 bytes (~128 KB)
//   [satoff..) satmap   : 1 bit per clause, ~512 KB, atomicOr (no-return,
//              fire-and-forget, no pre-check -> no L2 invalidate ping-pong)
// All rebuilt every call (ws re-poisoned to 0xAA before every timed launch).
// ---------------------------------------------------------------------------

__global__ void prep(const float* __restrict__ preds,
                     unsigned long long* __restrict__ predbits,
                     uint4* __restrict__ satz,
                     unsigned* __restrict__ hdr,
                     int n_vars,
                     const int* __restrict__ nc_p) {
    const int gid = blockIdx.x * blockDim.x + threadIdx.x;
    const int stride = gridDim.x * blockDim.x;

    // pack preds -> 1 bit per var
    const int nv64 = (n_vars + 63) & ~63;
    for (int i = gid; i < nv64; i += stride) {
        bool b = false;
        if (i < n_vars) b = (preds[i] >= 0.5f);
        const unsigned long long m = __ballot(b);
        if ((threadIdx.x & 63) == 0) predbits[i >> 6] = m;
    }

    // zero the 512 KB clause bitmap
    const int nc = *nc_p;
    const int satw16 = (((nc + 31) >> 5) + 3) >> 2;   // uint4 count
    const uint4 z = {0u, 0u, 0u, 0u};
    for (int i = gid; i < satw16; i += stride) satz[i] = z;

    if (gid < 8) hdr[gid] = 0u;
}

__device__ __forceinline__ void proc4(iv4 l, iv4 c, int nv,
                                      const unsigned* __restrict__ predbits,
                                      unsigned* __restrict__ sat) {
    #pragma unroll
    for (int k = 0; k < 4; ++k) {
        const int lit = l[k];
        const int cls = c[k];
        const bool pos = lit < nv;
        const int v = pos ? lit : lit - nv;
        const unsigned pb = predbits[v >> 5];        // hot 128 KB, L2-served
        const bool pbit = ((pb >> (v & 31)) & 1u) != 0u;
        if (pbit == pos) {
            // fire-and-forget device atomic: result unused -> no response wait
            atomicOr(&sat[((unsigned)cls) >> 5], 1u << (cls & 31));
        }
    }
}

__global__ void scatter_sat(const int* __restrict__ lits,
                            const int* __restrict__ clauses,
                            const unsigned* __restrict__ predbits,
                            unsigned* __restrict__ sat,
                            int n_edges, int n_vars) {
    const int tid = blockIdx.x * blockDim.x + threadIdx.x;
    const int T = gridDim.x * blockDim.x;
    const int n4 = n_edges >> 2;

    const iv4* __restrict__ l4 = reinterpret_cast<const iv4*>(lits);
    const iv4* __restrict__ c4 = reinterpret_cast<const iv4*>(clauses);

    int i = tid;
    // 2-wide unroll: two independent 16B NT load-pairs in flight per iter
    for (; i + T < n4; i += 2 * T) {
        const iv4 l0 = __builtin_nontemporal_load(&l4[i]);
        const iv4 c0 = __builtin_nontemporal_load(&c4[i]);
        const iv4 l1 = __builtin_nontemporal_load(&l4[i + T]);
        const iv4 c1 = __builtin_nontemporal_load(&c4[i + T]);
        proc4(l0, c0, n_vars, predbits, sat);
        proc4(l1, c1, n_vars, predbits, sat);
    }
    for (; i < n4; i += T) {
        const iv4 l = __builtin_nontemporal_load(&l4[i]);
        const iv4 c = __builtin_nontemporal_load(&c4[i]);
        proc4(l, c, n_vars, predbits, sat);
    }
    // scalar tail (n_edges not multiple of 4)
    for (int j = (n4 << 2) + tid; j < n_edges; j += T) {
        const int lit = lits[j];
        const int cls = clauses[j];
        const bool pos = lit < n_vars;
        const int v = pos ? lit : lit - n_vars;
        const unsigned pb = predbits[v >> 5];
        const bool pbit = ((pb >> (v & 31)) & 1u) != 0u;
        if (pbit == pos)
            atomicOr(&sat[((unsigned)cls) >> 5], 1u << (cls & 31));
    }
}

__global__ void reduce_finalize(const uint4* __restrict__ sat16,
                                unsigned* __restrict__ nsat,
                                unsigned* __restrict__ done,
                                float* __restrict__ out,
                                const int* __restrict__ nc_p,
                                int n_vars) {
    const int nc = *nc_p;
    const int n16 = (((nc + 31) >> 5) + 3) >> 2;
    const int tid = blockIdx.x * blockDim.x + threadIdx.x;
    const int stride = gridDim.x * blockDim.x;

    unsigned acc = 0;
    for (int i = tid; i < n16; i += stride) {
        const uint4 v = sat16[i];
        acc += __popc(v.x) + __popc(v.y) + __popc(v.z) + __popc(v.w);
    }

    #pragma unroll
    for (int off = 32; off > 0; off >>= 1) acc += __shfl_down(acc, off);

    __shared__ unsigned smem[BLOCK / 64];
    const int lane = threadIdx.x & 63;
    const int wid  = threadIdx.x >> 6;
    if (lane == 0) smem[wid] = acc;
    __syncthreads();

    if (threadIdx.x == 0) {
        unsigned bsum = 0;
        #pragma unroll
        for (int w = 0; w < BLOCK / 64; ++w) bsum += smem[w];
        atomicAdd(nsat, bsum);
        __threadfence();
        const unsigned ticket = atomicAdd(done, 1u);
        if (ticket == (unsigned)(gridDim.x - 1)) {
            const unsigned total = atomicAdd(nsat, 0u);
            *out = ((float)nc - (float)total) / (float)n_vars;
        }
    }
}

extern "C" void kernel_launch(void* const* d_in, const int* in_sizes, int n_in,
                              void* d_out, int out_size, void* d_ws, size_t ws_size,
                              hipStream_t stream) {
    const float* preds   = (const float*)d_in[0];
    const int*   lits    = (const int*)d_in[1];
    const int*   clauses = (const int*)d_in[2];
    const int*   nc_p    = (const int*)d_in[4];   // n_clauses (device scalar)
    const int    n_vars  = in_sizes[0];
    const int    n_edges = in_sizes[1];

    float* out = (float*)d_out;
    unsigned char* ws = (unsigned char*)d_ws;
    unsigned* hdr = (unsigned*)ws;                 // [0]=nsat [1]=done
    unsigned long long* predbits = (unsigned long long*)(ws + 64);
    const size_t predbits_bytes = ((size_t)((n_vars + 63) / 64)) * 8;
    size_t satoff = 64 + predbits_bytes;
    satoff = (satoff + 63) & ~(size_t)63;          // 64B align bitmap
    unsigned* satmap = (unsigned*)(ws + satoff);

    prep<<<1024, BLOCK, 0, stream>>>(preds, predbits, (uint4*)satmap, hdr,
                                     n_vars, nc_p);
    scatter_sat<<<2048, BLOCK, 0, stream>>>(lits, clauses,
                                            (const unsigned*)predbits, satmap,
                                            n_edges, n_vars);
    reduce_finalize<<<128, BLOCK, 0, stream>>>((const uint4*)satmap,
                                               hdr, hdr + 1, out, nc_p, n_vars);
}